// Round 4
// baseline (449.631 us; speedup 1.0000x reference)
//
#include <hip/hip_runtime.h>

#define LOG2PI 1.8378770664093453f
#define LN2    0.6931471805599453f

typedef short short8 __attribute__((ext_vector_type(8)));
typedef float f32x4 __attribute__((ext_vector_type(4)));

__device__ __forceinline__ unsigned short f2bf(float f) {
    unsigned int u = __builtin_bit_cast(unsigned int, f);
    u = (u + 0x7FFFu + ((u >> 16) & 1u)) >> 16;   // RNE
    return (unsigned short)u;
}
__device__ __forceinline__ float bf2f(unsigned short h) {
    unsigned int u = ((unsigned int)h) << 16;
    return __builtin_bit_cast(float, u);
}
__device__ __forceinline__ short8 pack8(float4 f0, float4 f1) {
    short8 r;
    r[0] = (short)f2bf(f0.x); r[1] = (short)f2bf(f0.y);
    r[2] = (short)f2bf(f0.z); r[3] = (short)f2bf(f0.w);
    r[4] = (short)f2bf(f1.x); r[5] = (short)f2bf(f1.y);
    r[6] = (short)f2bf(f1.z); r[7] = (short)f2bf(f1.w);
    return r;
}
__device__ __forceinline__ float rdlane(float v, int lane) {
    return __builtin_bit_cast(float, __builtin_amdgcn_readlane(__builtin_bit_cast(int, v), lane));
}

// ---------------------------------------------------------------------------
// K1: Gauss-Jordan in-place inverse, lane t = COLUMN t in regs a[0..63].
// j-loop FULLY UNROLLED: every readlane has a compile-time lane index and all
// i==j / t==j cases resolve at compile time. Inner body = readlane + fma only
// (the lane-j rjsp=1+pinv trick makes one fma correct for both the generic
// element and the pivot column). ~8.5k VALU instrs, chain ~1.7k cyc.
// Outputs: M=cov^-1 as MFMA B-fragments (bf16), v2 = 2*M*c,
// cdet = D*log2pi + logdet + c^T M c, acc = 0.  32 blocks x 64 threads.
// ---------------------------------------------------------------------------
__global__ __launch_bounds__(64) void prep_kernel(
    const float* __restrict__ cov, const float* __restrict__ centroid,
    unsigned short* __restrict__ wW, float* __restrict__ wV2,
    float* __restrict__ wC, float* __restrict__ wAcc)
{
    __shared__ float Mi[64 * 65];
    const int k = blockIdx.x;
    const int t = threadIdx.x;       // 0..63 = owned column

    float a[64];                     // a[i] = A[i][t]
#pragma unroll
    for (int i = 0; i < 64; ++i)
        a[i] = cov[(size_t)k * 4096 + i * 64 + t];

    if (k == 0 && t == 0) wAcc[0] = 0.0f;   // ws re-poisoned each launch

    float ld2 = 0.0f;                // sum log2(pivot)
#pragma unroll
    for (int j = 0; j < 64; ++j) {
        float p = rdlane(a[j], j);             // pivot (const-lane readlane)
        float pinv = __builtin_amdgcn_rcpf(p);
        ld2 += __log2f(p);
        float rjs = a[j] * pinv;               // scaled pivot row (lane j: 1)
        bool cm = (t == j);                    // one v_cmp per step
        a[j] = cm ? pinv : rjs;                // pivot row done (diag = 1/p)
        float rjsp = cm ? (1.0f + pinv) : rjs; // lane-j fixup for pivot column
#pragma unroll
        for (int i = 0; i < 64; ++i) {
            if (i == j) continue;
            float cji = rdlane(a[i], j);       // old A[i][j] (const lane)
            a[i] = fmaf(-cji, rjsp, a[i]);     // generic + pivot-col in one fma
        }
    }
    // a[i] = M[i][t] = inv(cov) column t

#pragma unroll
    for (int i = 0; i < 64; ++i) Mi[i * 65 + t] = a[i];
    __syncthreads();

    // y = (M c)_t ; v2 = 2y ; cMc = sum c_d y_d
    float cme = centroid[k * 64 + t];
    float y = 0.0f;
#pragma unroll
    for (int e = 0; e < 64; ++e)
        y = fmaf(Mi[t * 65 + e], rdlane(cme, e), y);
    wV2[k * 64 + t] = 2.0f * y;
    float cy = cme * y;
#pragma unroll
    for (int off = 32; off > 0; off >>= 1) cy += __shfl_down(cy, off);
    if (t == 0) wC[k] = 64.0f * LOG2PI + ld2 * LN2 + cy;

    // Pack M rows as MFMA B-fragments: frag for n-tile gnt=k*4+ntl, half s2,
    // lane l holds M[d = ntl*16 + (l&15)][e0 .. e0+7], e0 = s2*32 + (l>>4)*8.
    {
        const int m = t & 15, qd = t >> 4;
        uint4* wf = (uint4*)wW;
#pragma unroll
        for (int ntl = 0; ntl < 4; ++ntl) {
            int d = ntl * 16 + m;
#pragma unroll
            for (int s2 = 0; s2 < 2; ++s2) {
                int e0 = s2 * 32 + qd * 8;
                float4 f0, f1;
                f0.x = Mi[d * 65 + e0 + 0]; f0.y = Mi[d * 65 + e0 + 1];
                f0.z = Mi[d * 65 + e0 + 2]; f0.w = Mi[d * 65 + e0 + 3];
                f1.x = Mi[d * 65 + e0 + 4]; f1.y = Mi[d * 65 + e0 + 5];
                f1.z = Mi[d * 65 + e0 + 6]; f1.w = Mi[d * 65 + e0 + 7];
                short8 pk = pack8(f0, f1);
                wf[((k * 4 + ntl) * 2 + s2) * 64 + t] = __builtin_bit_cast(uint4, pk);
            }
        }
    }
}

// ---------------------------------------------------------------------------
// K2: fused gather + GEMM Z = X M^T (mfma 16x16x32 bf16) + epilogue
//     quad = sum_d x_d (z_d - v2_d) + cMc, weighted by resp, one atomic.
// Grid: 512 blocks x 256 thr; block = 128 rows x full N=2048; wave = 8 k's.
// emb/pi rows fetched exactly once chip-wide.
// ---------------------------------------------------------------------------
__global__ __launch_bounds__(256) void main_kernel(
    const float* __restrict__ emb, const float* __restrict__ pi,
    const int* __restrict__ labels, const unsigned short* __restrict__ wW,
    const float* __restrict__ wV2, const float* __restrict__ wC,
    float* __restrict__ wAcc)
{
    __shared__ int lab[128];
    __shared__ unsigned short Xs[128 * 72];   // bf16 x-tile, stride 72 (16B align + bank-spread)
    __shared__ float Rg[128 * 36];            // resp tile, stride 36
    __shared__ float vq[2048];
    __shared__ float cdet[32];
    __shared__ float red[4];

    const int tid = threadIdx.x;
    const int row0 = blockIdx.x * 128;

    if (tid < 128) lab[tid] = labels[row0 + tid];
    if (tid < 32) cdet[tid] = wC[tid];
    {
        const float4* v4 = (const float4*)wV2;
        *(float4*)&vq[tid * 8]     = v4[tid * 2];
        *(float4*)&vq[tid * 8 + 4] = v4[tid * 2 + 1];
    }
    __syncthreads();   // lab ready

    // stage X tile (bf16) — each thread: half a row (32 floats)
    {
        int r = tid >> 1, h = tid & 1;
        const float4* e4 = (const float4*)(emb + (size_t)lab[r] * 64 + h * 32);
#pragma unroll
        for (int q = 0; q < 4; ++q) {
            float4 f0 = e4[q * 2], f1 = e4[q * 2 + 1];
            short8 pk = pack8(f0, f1);
            *(short8*)&Xs[r * 72 + h * 32 + q * 8] = pk;
        }
    }
    // stage resp tile (all 32 k's per row)
    {
        const float4* pi4 = (const float4*)pi;
#pragma unroll
        for (int it = 0; it < 4; ++it) {
            int id = it * 256 + tid;
            int r = id >> 3, c = id & 7;
            float4 f = pi4[(size_t)lab[r] * 8 + c];
            *(float4*)&Rg[r * 36 + c * 4] = f;
        }
    }
    __syncthreads();

    const int w = tid >> 6, l = tid & 63;
    const int m = l & 15, qd = l >> 4;

    // A fragments: 8 row-tiles x 2 k-halves from LDS (16B reads)
    short8 afr[8][2];
#pragma unroll
    for (int rt = 0; rt < 8; ++rt) {
        int row = rt * 16 + m;
#pragma unroll
        for (int s = 0; s < 2; ++s)
            afr[rt][s] = *(const short8*)&Xs[row * 72 + s * 32 + qd * 8];
    }

    float qa[8][4] = {};
    float part = 0.0f;
    const uint4* wf4 = (const uint4*)wW;

    for (int nt = 0; nt < 32; ++nt) {
        int gnt = w * 32 + nt;
        uint4 u0 = wf4[(gnt * 2 + 0) * 64 + l];   // coalesced 1KB/instr
        uint4 u1 = wf4[(gnt * 2 + 1) * 64 + l];
        short8 b0 = __builtin_bit_cast(short8, u0);
        short8 b1 = __builtin_bit_cast(short8, u1);
        float vv = vq[gnt * 16 + m];
        int dcol = (nt & 3) * 16 + m;             // column within the k's D=64
#pragma unroll
        for (int rt = 0; rt < 8; ++rt) {
            f32x4 cc = {0.0f, 0.0f, 0.0f, 0.0f};
            cc = __builtin_amdgcn_mfma_f32_16x16x32_bf16(afr[rt][0], b0, cc, 0, 0, 0);
            cc = __builtin_amdgcn_mfma_f32_16x16x32_bf16(afr[rt][1], b1, cc, 0, 0, 0);
#pragma unroll
            for (int r2 = 0; r2 < 4; ++r2) {
                int rowl = rt * 16 + qd * 4 + r2;
                float xv = bf2f(Xs[rowl * 72 + dcol]);
                qa[rt][r2] = fmaf(xv, cc[r2] - vv, qa[rt][r2]);
            }
        }
        if ((nt & 3) == 3) {                      // k complete
            int kk = w * 8 + (nt >> 2);
            float cd = cdet[kk] * 0.0625f;        // 16 lanes share each (b,k)
#pragma unroll
            for (int rt = 0; rt < 8; ++rt) {
#pragma unroll
                for (int r2 = 0; r2 < 4; ++r2) {
                    int rowl = rt * 16 + qd * 4 + r2;
                    part = fmaf(Rg[rowl * 36 + kk], qa[rt][r2] + cd, part);
                    qa[rt][r2] = 0.0f;
                }
            }
        }
    }

    for (int off = 32; off > 0; off >>= 1) part += __shfl_down(part, off);
    if (l == 0) red[w] = part;
    __syncthreads();
    if (tid == 0) atomicAdd(wAcc, red[0] + red[1] + red[2] + red[3]);
}

__global__ void fin_kernel(const float* __restrict__ wAcc, float* __restrict__ out) {
    out[0] = fabsf(0.5f * wAcc[0]);
}

extern "C" void kernel_launch(void* const* d_in, const int* in_sizes, int n_in,
                              void* d_out, int out_size, void* d_ws, size_t ws_size,
                              hipStream_t stream) {
    const float* emb    = (const float*)d_in[0];
    const float* cent   = (const float*)d_in[1];
    const float* cov    = (const float*)d_in[2];
    const float* pi     = (const float*)d_in[3];
    const int*   labels = (const int*)d_in[4];
    float* out = (float*)d_out;

    char* w = (char*)d_ws;
    unsigned short* wW = (unsigned short*)w;              // 2048*64 bf16 = 262144 B
    float* wV2 = (float*)(w + 262144);                    // 2048 f32
    float* wC  = (float*)(w + 270336);                    // 32 f32
    float* wAcc = (float*)(w + 270464);                   // 1 f32

    prep_kernel<<<32, 64, 0, stream>>>(cov, cent, wW, wV2, wC, wAcc);
    main_kernel<<<512, 256, 0, stream>>>(emb, pi, labels, wW, wV2, wC, wAcc);
    fin_kernel<<<1, 1, 0, stream>>>(wAcc, out);
}

// Round 5
// 247.615 us; speedup vs baseline: 1.8158x; 1.8158x over previous
//
#include <hip/hip_runtime.h>

#define LOG2PI 1.8378770664093453f
#define LN2    0.6931471805599453f

typedef short short8 __attribute__((ext_vector_type(8)));
typedef float f32x4 __attribute__((ext_vector_type(4)));

__device__ __forceinline__ unsigned short f2bf(float f) {
    unsigned int u = __builtin_bit_cast(unsigned int, f);
    u = (u + 0x7FFFu + ((u >> 16) & 1u)) >> 16;   // RNE
    return (unsigned short)u;
}
__device__ __forceinline__ float bf2f(unsigned short h) {
    unsigned int u = ((unsigned int)h) << 16;
    return __builtin_bit_cast(float, u);
}
__device__ __forceinline__ short8 pack8(float4 f0, float4 f1) {
    short8 r;
    r[0] = (short)f2bf(f0.x); r[1] = (short)f2bf(f0.y);
    r[2] = (short)f2bf(f0.z); r[3] = (short)f2bf(f0.w);
    r[4] = (short)f2bf(f1.x); r[5] = (short)f2bf(f1.y);
    r[6] = (short)f2bf(f1.z); r[7] = (short)f2bf(f1.w);
    return r;
}
__device__ __forceinline__ float rdlane(float v, int lane) {
    return __builtin_bit_cast(float, __builtin_amdgcn_readlane(__builtin_bit_cast(int, v), lane));
}

// ---------------------------------------------------------------------------
// K1: block-parallel Gauss-Jordan inverse. 32 blocks (one per k) x 512 thr.
// Wave w owns rows w*8..w*8+7 (registers a[0..8], column = lane). Per step:
// pivot row broadcast via double-buffered LDS line (ONE barrier/step);
// pivot column via v_readlane(a[r], j) (r compile-time, j uniform SGPR).
// phase x jr loop structure keeps code ~2KB (no I$ thrash) and the owner's
// register index compile-time. rjsp trick: single fma handles generic +
// pivot-column cases. Outputs: M=cov^-1 as bf16 MFMA B-fragments, v2=2*M*c,
// cdet = D*log2pi + logdet + c^T M c, acc=0.
// ---------------------------------------------------------------------------
__global__ __launch_bounds__(512) void prep_kernel(
    const float* __restrict__ cov, const float* __restrict__ centroid,
    unsigned short* __restrict__ wW, float* __restrict__ wV2,
    float* __restrict__ wC, float* __restrict__ wAcc)
{
    __shared__ float rowbuf[2][64];
    __shared__ float Mi[64 * 65];
    const int k = blockIdx.x;
    const int tid = threadIdx.x;
    const int w = tid >> 6;          // wave 0..7, owns rows w*8..w*8+7
    const int l = tid & 63;          // column

    float a[8];
#pragma unroll
    for (int r = 0; r < 8; ++r)
        a[r] = cov[(size_t)k * 4096 + (w * 8 + r) * 64 + l];

    if (k == 0 && tid == 0) wAcc[0] = 0.0f;   // ws re-poisoned each launch

    float ld2 = 0.0f;                // sum log2(pivot), identical on all threads
    for (int phase = 0; phase < 8; ++phase) {
        const bool owner = (w == phase);
#pragma unroll
        for (int jr = 0; jr < 8; ++jr) {
            const int j = phase * 8 + jr;
            if (owner) rowbuf[jr & 1][l] = a[jr];
            __syncthreads();
            float prow = rowbuf[jr & 1][l];        // A[j][l]
            float p = rdlane(prow, j);             // pivot A[j][j]
            float pinv = __builtin_amdgcn_rcpf(p);
            ld2 += __log2f(p);
            float rjs = prow * pinv;               // scaled pivot row
            float rjsp = (l == j) ? 1.0f + pinv : rjs;  // pivot-column fixup
#pragma unroll
            for (int r = 0; r < 8; ++r) {
                float cji = rdlane(a[r], j);       // A[i][j], uniform lane
                a[r] = fmaf(-cji, rjsp, a[r]);     // generic + pivot-col
            }
            if (owner) a[jr] = (l == j) ? pinv : rjs;   // pivot row
        }
    }
    // a[r] = M[w*8+r][l] = inv(cov)

#pragma unroll
    for (int r = 0; r < 8; ++r) Mi[(w * 8 + r) * 65 + l] = a[r];
    __syncthreads();

    // wave 0: y = (M c)_t, v2 = 2y, cMc; cdet
    if (tid < 64) {
        const int t = tid;
        float cme = centroid[k * 64 + t];
        float y = 0.0f;
#pragma unroll
        for (int e = 0; e < 64; ++e)
            y = fmaf(Mi[t * 65 + e], rdlane(cme, e), y);
        wV2[k * 64 + t] = 2.0f * y;
        float cy = cme * y;
#pragma unroll
        for (int off = 32; off > 0; off >>= 1) cy += __shfl_down(cy, off);
        if (t == 0) wC[k] = 64.0f * LOG2PI + ld2 * LN2 + cy;
    }

    // Pack M as MFMA B-fragments, one 16B fragment-slot per thread:
    // frag (gnt=k*4+ntl, half s2), lane l holds M[d=ntl*16+(l&15)][e0..e0+7].
    {
        const int m = l & 15, qd = l >> 4;
        const int ntl = tid >> 7, s2 = (tid >> 6) & 1;
        const int d = ntl * 16 + m;
        const int e0 = s2 * 32 + qd * 8;
        float4 f0, f1;
        f0.x = Mi[d * 65 + e0 + 0]; f0.y = Mi[d * 65 + e0 + 1];
        f0.z = Mi[d * 65 + e0 + 2]; f0.w = Mi[d * 65 + e0 + 3];
        f1.x = Mi[d * 65 + e0 + 4]; f1.y = Mi[d * 65 + e0 + 5];
        f1.z = Mi[d * 65 + e0 + 6]; f1.w = Mi[d * 65 + e0 + 7];
        short8 pk = pack8(f0, f1);
        ((uint4*)wW)[((k * 4 + ntl) * 2 + s2) * 64 + l] = __builtin_bit_cast(uint4, pk);
    }
}

// ---------------------------------------------------------------------------
// K2: fused gather + GEMM Z = X M^T (mfma 16x16x32 bf16) + epilogue
//     quad = sum_d x_d (z_d - v2_d) + cMc, weighted by resp, one atomic.
// Grid: 512 blocks x 256 thr; block = 128 rows x full N=2048; wave = 8 k's.
// emb/pi rows fetched exactly once chip-wide.
// ---------------------------------------------------------------------------
__global__ __launch_bounds__(256) void main_kernel(
    const float* __restrict__ emb, const float* __restrict__ pi,
    const int* __restrict__ labels, const unsigned short* __restrict__ wW,
    const float* __restrict__ wV2, const float* __restrict__ wC,
    float* __restrict__ wAcc)
{
    __shared__ int lab[128];
    __shared__ unsigned short Xs[128 * 72];   // bf16 x-tile, stride 72
    __shared__ float Rg[128 * 36];            // resp tile, stride 36
    __shared__ float vq[2048];
    __shared__ float cdet[32];
    __shared__ float red[4];

    const int tid = threadIdx.x;
    const int row0 = blockIdx.x * 128;

    if (tid < 128) lab[tid] = labels[row0 + tid];
    if (tid < 32) cdet[tid] = wC[tid];
    {
        const float4* v4 = (const float4*)wV2;
        *(float4*)&vq[tid * 8]     = v4[tid * 2];
        *(float4*)&vq[tid * 8 + 4] = v4[tid * 2 + 1];
    }
    __syncthreads();   // lab ready

    // stage X tile (bf16) — each thread: half a row (32 floats)
    {
        int r = tid >> 1, h = tid & 1;
        const float4* e4 = (const float4*)(emb + (size_t)lab[r] * 64 + h * 32);
#pragma unroll
        for (int q = 0; q < 4; ++q) {
            float4 f0 = e4[q * 2], f1 = e4[q * 2 + 1];
            short8 pk = pack8(f0, f1);
            *(short8*)&Xs[r * 72 + h * 32 + q * 8] = pk;
        }
    }
    // stage resp tile (all 32 k's per row)
    {
        const float4* pi4 = (const float4*)pi;
#pragma unroll
        for (int it = 0; it < 4; ++it) {
            int id = it * 256 + tid;
            int r = id >> 3, c = id & 7;
            float4 f = pi4[(size_t)lab[r] * 8 + c];
            *(float4*)&Rg[r * 36 + c * 4] = f;
        }
    }
    __syncthreads();

    const int w = tid >> 6, l = tid & 63;
    const int m = l & 15, qd = l >> 4;

    // A fragments: 8 row-tiles x 2 k-halves from LDS (16B reads)
    short8 afr[8][2];
#pragma unroll
    for (int rt = 0; rt < 8; ++rt) {
        int row = rt * 16 + m;
#pragma unroll
        for (int s = 0; s < 2; ++s)
            afr[rt][s] = *(const short8*)&Xs[row * 72 + s * 32 + qd * 8];
    }

    float qa[8][4] = {};
    float part = 0.0f;
    const uint4* wf4 = (const uint4*)wW;

    for (int nt = 0; nt < 32; ++nt) {
        int gnt = w * 32 + nt;
        uint4 u0 = wf4[(gnt * 2 + 0) * 64 + l];   // coalesced 1KB/instr
        uint4 u1 = wf4[(gnt * 2 + 1) * 64 + l];
        short8 b0 = __builtin_bit_cast(short8, u0);
        short8 b1 = __builtin_bit_cast(short8, u1);
        float vv = vq[gnt * 16 + m];
        int dcol = (nt & 3) * 16 + m;             // column within the k's D=64
#pragma unroll
        for (int rt = 0; rt < 8; ++rt) {
            f32x4 cc = {0.0f, 0.0f, 0.0f, 0.0f};
            cc = __builtin_amdgcn_mfma_f32_16x16x32_bf16(afr[rt][0], b0, cc, 0, 0, 0);
            cc = __builtin_amdgcn_mfma_f32_16x16x32_bf16(afr[rt][1], b1, cc, 0, 0, 0);
#pragma unroll
            for (int r2 = 0; r2 < 4; ++r2) {
                int rowl = rt * 16 + qd * 4 + r2;
                float xv = bf2f(Xs[rowl * 72 + dcol]);
                qa[rt][r2] = fmaf(xv, cc[r2] - vv, qa[rt][r2]);
            }
        }
        if ((nt & 3) == 3) {                      // k complete
            int kk = w * 8 + (nt >> 2);
            float cd = cdet[kk] * 0.0625f;        // 16 lanes share each (b,k)
#pragma unroll
            for (int rt = 0; rt < 8; ++rt) {
#pragma unroll
                for (int r2 = 0; r2 < 4; ++r2) {
                    int rowl = rt * 16 + qd * 4 + r2;
                    part = fmaf(Rg[rowl * 36 + kk], qa[rt][r2] + cd, part);
                    qa[rt][r2] = 0.0f;
                }
            }
        }
    }

    for (int off = 32; off > 0; off >>= 1) part += __shfl_down(part, off);
    if (l == 0) red[w] = part;
    __syncthreads();
    if (tid == 0) atomicAdd(wAcc, red[0] + red[1] + red[2] + red[3]);
}

__global__ void fin_kernel(const float* __restrict__ wAcc, float* __restrict__ out) {
    out[0] = fabsf(0.5f * wAcc[0]);
}

extern "C" void kernel_launch(void* const* d_in, const int* in_sizes, int n_in,
                              void* d_out, int out_size, void* d_ws, size_t ws_size,
                              hipStream_t stream) {
    const float* emb    = (const float*)d_in[0];
    const float* cent   = (const float*)d_in[1];
    const float* cov    = (const float*)d_in[2];
    const float* pi     = (const float*)d_in[3];
    const int*   labels = (const int*)d_in[4];
    float* out = (float*)d_out;

    char* w = (char*)d_ws;
    unsigned short* wW = (unsigned short*)w;              // 2048*64 bf16 = 262144 B
    float* wV2 = (float*)(w + 262144);                    // 2048 f32
    float* wC  = (float*)(w + 270336);                    // 32 f32
    float* wAcc = (float*)(w + 270464);                   // 1 f32

    prep_kernel<<<32, 512, 0, stream>>>(cov, cent, wW, wV2, wC, wAcc);
    main_kernel<<<512, 256, 0, stream>>>(emb, pi, labels, wW, wV2, wC, wAcc);
    fin_kernel<<<1, 1, 0, stream>>>(wAcc, out);
}

// Round 6
// 245.049 us; speedup vs baseline: 1.8349x; 1.0105x over previous
//
#include <hip/hip_runtime.h>

#define LOG2PI 1.8378770664093453f
#define LN2    0.6931471805599453f

typedef short short8 __attribute__((ext_vector_type(8)));
typedef float f32x4 __attribute__((ext_vector_type(4)));

__device__ __forceinline__ unsigned short f2bf(float f) {
    unsigned int u = __builtin_bit_cast(unsigned int, f);
    u = (u + 0x7FFFu + ((u >> 16) & 1u)) >> 16;   // RNE
    return (unsigned short)u;
}
__device__ __forceinline__ float rdlane(float v, int lane) {
    return __builtin_bit_cast(float, __builtin_amdgcn_readlane(__builtin_bit_cast(int, v), lane));
}

// ---------------------------------------------------------------------------
// K1: block-parallel Gauss-Jordan inverse (unchanged from R5 except:
// sigma-permuted fragment pack + zeroing the completion counter).
// 32 blocks x 512 thr; wave w owns rows w*8..w*8+7, column = lane.
// Contraction-index permutation sigma(j) = (j&3)*16 + (j>>2) applied to the
// e-index of both X staging (main) and M fragment pack (here) — the GEMM dot
// product is invariant, and it makes main's epilogue x-reads contiguous.
// ---------------------------------------------------------------------------
__global__ __launch_bounds__(512) void prep_kernel(
    const float* __restrict__ cov, const float* __restrict__ centroid,
    unsigned short* __restrict__ wW, float* __restrict__ wV2,
    float* __restrict__ wC, float* __restrict__ wAcc, unsigned int* __restrict__ wCnt)
{
    __shared__ float rowbuf[2][64];
    __shared__ float Mi[64 * 65];
    const int k = blockIdx.x;
    const int tid = threadIdx.x;
    const int w = tid >> 6;          // wave 0..7, owns rows w*8..w*8+7
    const int l = tid & 63;          // column

    float a[8];
#pragma unroll
    for (int r = 0; r < 8; ++r)
        a[r] = cov[(size_t)k * 4096 + (w * 8 + r) * 64 + l];

    if (k == 0 && tid == 0) { wAcc[0] = 0.0f; wCnt[0] = 0u; }  // ws re-poisoned each launch

    float ld2 = 0.0f;                // sum log2(pivot), identical on all threads
    for (int phase = 0; phase < 8; ++phase) {
        const bool owner = (w == phase);
#pragma unroll
        for (int jr = 0; jr < 8; ++jr) {
            const int j = phase * 8 + jr;
            if (owner) rowbuf[jr & 1][l] = a[jr];
            __syncthreads();
            float prow = rowbuf[jr & 1][l];        // A[j][l]
            float p = rdlane(prow, j);             // pivot A[j][j]
            float pinv = __builtin_amdgcn_rcpf(p);
            ld2 += __log2f(p);
            float rjs = prow * pinv;               // scaled pivot row
            float rjsp = (l == j) ? 1.0f + pinv : rjs;  // pivot-column fixup
#pragma unroll
            for (int r = 0; r < 8; ++r) {
                float cji = rdlane(a[r], j);       // A[i][j], uniform lane
                a[r] = fmaf(-cji, rjsp, a[r]);     // generic + pivot-col
            }
            if (owner) a[jr] = (l == j) ? pinv : rjs;   // pivot row
        }
    }
    // a[r] = M[w*8+r][l] = inv(cov)

#pragma unroll
    for (int r = 0; r < 8; ++r) Mi[(w * 8 + r) * 65 + l] = a[r];
    __syncthreads();

    // wave 0: y = (M c)_t, v2 = 2y, cMc; cdet
    if (tid < 64) {
        const int t = tid;
        float cme = centroid[k * 64 + t];
        float y = 0.0f;
#pragma unroll
        for (int e = 0; e < 64; ++e)
            y = fmaf(Mi[t * 65 + e], rdlane(cme, e), y);
        wV2[k * 64 + t] = 2.0f * y;
        float cy = cme * y;
#pragma unroll
        for (int off = 32; off > 0; off >>= 1) cy += __shfl_down(cy, off);
        if (t == 0) wC[k] = 64.0f * LOG2PI + ld2 * LN2 + cy;
    }

    // Pack M as MFMA B-fragments with sigma-permuted e-index.
    // Fragment element i (0..7) of (frag gnt=k*4+ntl, half s2, lane l) holds
    // M[d = ntl*16+(l&15)][ (i&3)*16 + s2*8 + (l>>4)*2 + (i>>2) ].
    {
        const int m = l & 15, qd = l >> 4;
        const int ntl = tid >> 7, s2 = (tid >> 6) & 1;
        const int d = ntl * 16 + m;
        const int base = s2 * 8 + qd * 2;
        const float* Mr = &Mi[d * 65];
        short8 pk;
#pragma unroll
        for (int i = 0; i < 8; ++i)
            pk[i] = (short)f2bf(Mr[(i & 3) * 16 + base + (i >> 2)]);
        ((uint4*)wW)[((k * 4 + ntl) * 2 + s2) * 64 + l] = __builtin_bit_cast(uint4, pk);
    }
}

// ---------------------------------------------------------------------------
// K2: fused gather + GEMM Z = X M^T (mfma 16x16x32 bf16, sigma-permuted
// contraction) + epilogue quad = sum_d x_d (z_d - v2_d) + cMc, weighted by
// resp; per-lane x-values preloaded once (32 ds_read_b64, 8x reuse in regs);
// grid-wide finish fused via completion counter (last block writes |sum|/2).
// Grid: 512 blocks x 256 thr; block = 128 rows x full N=2048; wave = 8 k's.
// ---------------------------------------------------------------------------
__global__ __launch_bounds__(256) void main_kernel(
    const float* __restrict__ emb, const float* __restrict__ pi,
    const int* __restrict__ labels, const unsigned short* __restrict__ wW,
    const float* __restrict__ wV2, const float* __restrict__ wC,
    float* __restrict__ wAcc, unsigned int* __restrict__ wCnt,
    float* __restrict__ out)
{
    __shared__ int lab[128];
    __shared__ unsigned short Xs[128 * 72];   // sigma-permuted bf16 x-tile, stride 72
    __shared__ float Rg[128 * 36];            // resp tile, stride 36
    __shared__ float vq[2048];
    __shared__ float cdet[32];
    __shared__ float red[4];

    const int tid = threadIdx.x;
    const int row0 = blockIdx.x * 128;

    if (tid < 128) lab[tid] = labels[row0 + tid];
    if (tid < 32) cdet[tid] = wC[tid];
    {
        const float4* v4 = (const float4*)wV2;
        *(float4*)&vq[tid * 8]     = v4[tid * 2];
        *(float4*)&vq[tid * 8 + 4] = v4[tid * 2 + 1];
    }
    __syncthreads();   // lab ready

    // stage X tile (bf16, sigma order): thread = (row r, half h); storage col
    // j = h*32 + mm*4 + c16 holds x[r][c16*16 + h*8 + mm], mm in [0,8).
    {
        int r = tid >> 1, h = tid & 1;
        const float* erow = emb + (size_t)lab[r] * 64 + h * 8;
        float xv[4][8];
#pragma unroll
        for (int c16 = 0; c16 < 4; ++c16) {
            float4 f0 = *(const float4*)(erow + c16 * 16);
            float4 f1 = *(const float4*)(erow + c16 * 16 + 4);
            xv[c16][0] = f0.x; xv[c16][1] = f0.y; xv[c16][2] = f0.z; xv[c16][3] = f0.w;
            xv[c16][4] = f1.x; xv[c16][5] = f1.y; xv[c16][6] = f1.z; xv[c16][7] = f1.w;
        }
#pragma unroll
        for (int g = 0; g < 4; ++g) {
            short8 pk;
#pragma unroll
            for (int idx = 0; idx < 8; ++idx)
                pk[idx] = (short)f2bf(xv[idx & 3][g * 2 + (idx >> 2)]);
            *(short8*)&Xs[r * 72 + h * 32 + g * 8] = pk;
        }
    }
    // stage resp tile (all 32 k's per row)
    {
        const float4* pi4 = (const float4*)pi;
#pragma unroll
        for (int it = 0; it < 4; ++it) {
            int id = it * 256 + tid;
            int r = id >> 3, c = id & 7;
            float4 f = pi4[(size_t)lab[r] * 8 + c];
            *(float4*)&Rg[r * 36 + c * 4] = f;
        }
    }
    __syncthreads();

    const int w = tid >> 6, l = tid & 63;
    const int m = l & 15, qd = l >> 4;

    // A fragments: 8 row-tiles x 2 k-halves from LDS (16B reads, sigma order)
    short8 afr[8][2];
#pragma unroll
    for (int rt = 0; rt < 8; ++rt) {
        int row = rt * 16 + m;
#pragma unroll
        for (int s = 0; s < 2; ++s)
            afr[rt][s] = *(const short8*)&Xs[row * 72 + s * 32 + qd * 8];
    }
    // x preload for epilogue: xr[rt][r2] = 4 bf16 {x[rowl][c16*16+m], c16=0..3}
    uint2 xr[8][4];
#pragma unroll
    for (int rt = 0; rt < 8; ++rt)
#pragma unroll
        for (int r2 = 0; r2 < 4; ++r2) {
            int rowl = rt * 16 + qd * 4 + r2;
            xr[rt][r2] = *(const uint2*)&Xs[rowl * 72 + m * 4];
        }

    float part = 0.0f;
    const uint4* wf4 = (const uint4*)wW;

    for (int q = 0; q < 8; ++q) {            // one component k per iteration
        int kk = w * 8 + q;
        float qa[8][4];
#pragma unroll
        for (int rt = 0; rt < 8; ++rt)
#pragma unroll
            for (int r2 = 0; r2 < 4; ++r2) qa[rt][r2] = 0.0f;

#pragma unroll
        for (int c16 = 0; c16 < 4; ++c16) {
            int gnt = w * 32 + q * 4 + c16;
            uint4 u0 = wf4[(gnt * 2 + 0) * 64 + l];   // coalesced 1KB/instr
            uint4 u1 = wf4[(gnt * 2 + 1) * 64 + l];
            short8 b0 = __builtin_bit_cast(short8, u0);
            short8 b1 = __builtin_bit_cast(short8, u1);
            float vv = vq[gnt * 16 + m];
#pragma unroll
            for (int rt = 0; rt < 8; ++rt) {
                f32x4 cc = {0.0f, 0.0f, 0.0f, 0.0f};
                cc = __builtin_amdgcn_mfma_f32_16x16x32_bf16(afr[rt][0], b0, cc, 0, 0, 0);
                cc = __builtin_amdgcn_mfma_f32_16x16x32_bf16(afr[rt][1], b1, cc, 0, 0, 0);
#pragma unroll
                for (int r2 = 0; r2 < 4; ++r2) {
                    uint2 u = xr[rt][r2];
                    unsigned int p = (c16 & 2) ? u.y : u.x;
                    unsigned int bits = (c16 & 1) ? (p & 0xFFFF0000u) : (p << 16);
                    float xvf = __builtin_bit_cast(float, bits);
                    qa[rt][r2] = fmaf(xvf, cc[r2] - vv, qa[rt][r2]);
                }
            }
        }
        float cd = cdet[kk] * 0.0625f;       // /16: 16 lanes share each (b,k)
#pragma unroll
        for (int rt = 0; rt < 8; ++rt)
#pragma unroll
            for (int r2 = 0; r2 < 4; ++r2) {
                int rowl = rt * 16 + qd * 4 + r2;
                part = fmaf(Rg[rowl * 36 + kk], qa[rt][r2] + cd, part);
            }
    }

    for (int off = 32; off > 0; off >>= 1) part += __shfl_down(part, off);
    if (l == 0) red[w] = part;
    __syncthreads();
    if (tid == 0) {
        atomicAdd(wAcc, red[0] + red[1] + red[2] + red[3]);
        __threadfence();
        unsigned int done = atomicAdd(wCnt, 1u);
        if (done == gridDim.x - 1) {         // last block finishes the reduction
            float total = atomicAdd(wAcc, 0.0f);   // coherent L2 read-back
            out[0] = fabsf(0.5f * total);
        }
    }
}

extern "C" void kernel_launch(void* const* d_in, const int* in_sizes, int n_in,
                              void* d_out, int out_size, void* d_ws, size_t ws_size,
                              hipStream_t stream) {
    const float* emb    = (const float*)d_in[0];
    const float* cent   = (const float*)d_in[1];
    const float* cov    = (const float*)d_in[2];
    const float* pi     = (const float*)d_in[3];
    const int*   labels = (const int*)d_in[4];
    float* out = (float*)d_out;

    char* w = (char*)d_ws;
    unsigned short* wW = (unsigned short*)w;              // 2048*64 bf16 = 262144 B
    float* wV2 = (float*)(w + 262144);                    // 2048 f32
    float* wC  = (float*)(w + 270336);                    // 32 f32
    float* wAcc = (float*)(w + 270464);                   // 1 f32
    unsigned int* wCnt = (unsigned int*)(w + 270468);     // completion counter

    prep_kernel<<<32, 512, 0, stream>>>(cov, cent, wW, wV2, wC, wAcc, wCnt);
    main_kernel<<<512, 256, 0, stream>>>(emb, pi, labels, wW, wV2, wC, wAcc, wCnt, out);
}